// Round 1
// baseline (201.982 us; speedup 1.0000x reference)
//
#include <hip/hip_runtime.h>

// Cosine-similarity attention context:
//   dots[s]  = keys[s,:] . q
//   cos[s]   = dots[s] / (||q|| * ||keys[s,:]||)
//   ctx[h]   = sum_s cos[s] * keys[s,h]
// keys = 32768 x 1024 f32 (128 MiB) -> HBM-bound, single pass over keys.
//
// R1 changes vs 194.9us baseline:
//  - main: 2 rows per iteration, 4 interleaved shuffle-reduce chains
//    (doubles in-flight bytes/wave to 8 KiB, gives the serial DS chain
//    4-way ILP; at 2 waves/SIMD the 6-level shfl chain was exposed).
//  - epilogue: reduce kernel rewritten as 16 blocks x 64 cols, direct
//    write (no atomics), which also removes the out-memset dispatch.

constexpr int H   = 1024;   // hidden dim (fixed by problem)
constexpr int TPB = 256;    // 4 waves per block
constexpr int WPB = TPB / 64;
constexpr int NBLOCKS = 512;       // 2048 waves = 8 waves/CU (2 blocks/CU exactly)
constexpr int RED_BLOCKS = H / 64; // 16 reduce blocks, 64 cols each

// One row per wave: lane holds columns {j*256 + 4*lane + k}, j=0..3, k=0..3
// (four fully-coalesced float4 loads per row).

template <bool USE_WS>
__global__ __launch_bounds__(TPB, 2)
void cosctx_main(const float* __restrict__ q,
                 const float* __restrict__ keys,
                 int S,
                 float* __restrict__ out,
                 float* __restrict__ ws)
{
    const int lane  = threadIdx.x & 63;
    const int wave  = threadIdx.x >> 6;
    const int gwave = blockIdx.x * WPB + wave;
    const int nw    = gridDim.x * WPB;

    const float4* q4 = reinterpret_cast<const float4*>(q);
    const float4* k4 = reinterpret_cast<const float4*>(keys);

    // --- query fragment + 1/||q|| (redundant per wave; q is 4 KiB, L2-hot) ---
    float4 qv[4];
#pragma unroll
    for (int j = 0; j < 4; ++j) qv[j] = q4[j * 64 + lane];

    float qsq = 0.f;
#pragma unroll
    for (int j = 0; j < 4; ++j)
        qsq += qv[j].x * qv[j].x + qv[j].y * qv[j].y +
               qv[j].z * qv[j].z + qv[j].w * qv[j].w;
#pragma unroll
    for (int off = 32; off > 0; off >>= 1) qsq += __shfl_down(qsq, off, 64);
    const float inv_qn = rsqrtf(__shfl(qsq, 0, 64));

    float4 acc[4];
#pragma unroll
    for (int j = 0; j < 4; ++j) acc[j] = make_float4(0.f, 0.f, 0.f, 0.f);

    // --- single pass over rows, 2 rows/iter, 1-pair prefetch pipeline ---
    int ra = gwave;
    int rb = gwave + nw;
    float4 ka[4], kb[4];
    if (ra < S) {
        const float4* kr = k4 + (size_t)ra * (H / 4);
#pragma unroll
        for (int j = 0; j < 4; ++j) ka[j] = kr[j * 64 + lane];
    }
    if (rb < S) {
        const float4* kr = k4 + (size_t)rb * (H / 4);
#pragma unroll
        for (int j = 0; j < 4; ++j) kb[j] = kr[j * 64 + lane];
    }

    while (ra < S) {
        const int rc = ra + 2 * nw;
        const int rd = rb + 2 * nw;
        float4 kc[4], kd[4];
        if (rc < S) {
            const float4* kr = k4 + (size_t)rc * (H / 4);
#pragma unroll
            for (int j = 0; j < 4; ++j) kc[j] = kr[j * 64 + lane];
        }
        if (rd < S) {
            const float4* kr = k4 + (size_t)rd * (H / 4);
#pragma unroll
            for (int j = 0; j < 4; ++j) kd[j] = kr[j * 64 + lane];
        }

        const bool hasB = (rb < S);   // wave-uniform (rb depends only on gwave)

        float dotA = 0.f, ksqA = 0.f, dotB = 0.f, ksqB = 0.f;
#pragma unroll
        for (int j = 0; j < 4; ++j) {
            dotA += ka[j].x * qv[j].x + ka[j].y * qv[j].y +
                    ka[j].z * qv[j].z + ka[j].w * qv[j].w;
            ksqA += ka[j].x * ka[j].x + ka[j].y * ka[j].y +
                    ka[j].z * ka[j].z + ka[j].w * ka[j].w;
        }
        if (hasB) {
#pragma unroll
            for (int j = 0; j < 4; ++j) {
                dotB += kb[j].x * qv[j].x + kb[j].y * qv[j].y +
                        kb[j].z * qv[j].z + kb[j].w * qv[j].w;
                ksqB += kb[j].x * kb[j].x + kb[j].y * kb[j].y +
                        kb[j].z * kb[j].z + kb[j].w * kb[j].w;
            }
        }
        // four interleaved (independent) shuffle-reduce chains, no barriers
#pragma unroll
        for (int off = 32; off > 0; off >>= 1) {
            dotA += __shfl_down(dotA, off, 64);
            ksqA += __shfl_down(ksqA, off, 64);
            dotB += __shfl_down(dotB, off, 64);
            ksqB += __shfl_down(ksqB, off, 64);
        }
        const float scoreA = __shfl(dotA, 0, 64) * inv_qn *
                             rsqrtf(__shfl(ksqA, 0, 64));
#pragma unroll
        for (int j = 0; j < 4; ++j) {
            acc[j].x += scoreA * ka[j].x;
            acc[j].y += scoreA * ka[j].y;
            acc[j].z += scoreA * ka[j].z;
            acc[j].w += scoreA * ka[j].w;
        }
        if (hasB) {
            const float scoreB = __shfl(dotB, 0, 64) * inv_qn *
                                 rsqrtf(__shfl(ksqB, 0, 64));
#pragma unroll
            for (int j = 0; j < 4; ++j) {
                acc[j].x += scoreB * kb[j].x;
                acc[j].y += scoreB * kb[j].y;
                acc[j].z += scoreB * kb[j].z;
                acc[j].w += scoreB * kb[j].w;
            }
        }
#pragma unroll
        for (int j = 0; j < 4; ++j) { ka[j] = kc[j]; kb[j] = kd[j]; }
        ra = rc;
        rb = rd;
    }

    // --- block reduce: 4 wave-partials -> 1 block-partial [H] ---
    __shared__ float sacc[WPB][H];   // 16 KiB
    float4* sa4 = reinterpret_cast<float4*>(sacc[wave]);
#pragma unroll
    for (int j = 0; j < 4; ++j) sa4[j * 64 + lane] = acc[j];
    __syncthreads();

    float4 v = make_float4(0.f, 0.f, 0.f, 0.f);
#pragma unroll
    for (int w = 0; w < WPB; ++w) {
        float4 u = reinterpret_cast<const float4*>(sacc[w])[threadIdx.x];
        v.x += u.x; v.y += u.y; v.z += u.z; v.w += u.w;
    }

    if (USE_WS) {
        // block-partial to workspace, non-atomic; reduced by second kernel
        reinterpret_cast<float4*>(ws)[(size_t)blockIdx.x * (H / 4) + threadIdx.x] = v;
    } else {
        // fallback: device-scope atomics straight into out (out pre-zeroed)
        const int c = threadIdx.x * 4;
        atomicAdd(out + c + 0, v.x);
        atomicAdd(out + c + 1, v.y);
        atomicAdd(out + c + 2, v.z);
        atomicAdd(out + c + 3, v.w);
    }
}

// Reduce NBLOCKS x H block-partials (2 MiB, L2/L3-hot) into out.
// 16 blocks, one per 64-column slab; no atomics, writes out directly
// (covers all H columns -> no out-memset needed).
__global__ __launch_bounds__(256)
void cosctx_reduce(const float* __restrict__ ws, float* __restrict__ out)
{
    const float4* w4 = reinterpret_cast<const float4*>(ws);
    const int cq = threadIdx.x & 15;          // col-quad within 64-col slab
    const int rg = threadIdx.x >> 4;          // 0..15 row-group
    const int base = blockIdx.x * 16 + cq;    // float4 index within a row

    float4 s = make_float4(0.f, 0.f, 0.f, 0.f);
    for (int b = rg; b < NBLOCKS; b += 16) {
        float4 u = w4[(size_t)b * (H / 4) + base];
        s.x += u.x; s.y += u.y; s.z += u.z; s.w += u.w;
    }

    __shared__ float4 red[16][16];
    red[rg][cq] = s;
    __syncthreads();

    if (threadIdx.x < 16) {
        float4 r = red[0][threadIdx.x];
#pragma unroll
        for (int g = 1; g < 16; ++g) {
            float4 u = red[g][threadIdx.x];
            r.x += u.x; r.y += u.y; r.z += u.z; r.w += u.w;
        }
        reinterpret_cast<float4*>(out)[blockIdx.x * 16 + threadIdx.x] = r;
    }
}

extern "C" void kernel_launch(void* const* d_in, const int* in_sizes, int n_in,
                              void* d_out, int out_size, void* d_ws, size_t ws_size,
                              hipStream_t stream)
{
    const float* q    = (const float*)d_in[0];
    const float* keys = (const float*)d_in[1];
    float* out        = (float*)d_out;
    const int S = in_sizes[1] / H;

    const size_t ws_need = (size_t)NBLOCKS * H * sizeof(float);
    if (ws_size >= ws_need) {
        // no out-memset: cosctx_reduce writes every output element directly
        cosctx_main<true><<<NBLOCKS, TPB, 0, stream>>>(q, keys, S, out, (float*)d_ws);
        cosctx_reduce<<<RED_BLOCKS, 256, 0, stream>>>((const float*)d_ws, out);
    } else {
        // fallback: d_out poisoned 0xAA before every call -> zero it, then atomics
        hipMemsetAsync(out, 0, H * sizeof(float), stream);
        cosctx_main<false><<<NBLOCKS, TPB, 0, stream>>>(q, keys, S, out, nullptr);
    }
}

// Round 2
// 200.046 us; speedup vs baseline: 1.0097x; 1.0097x over previous
//
#include <hip/hip_runtime.h>

// Cosine-similarity attention context:
//   dots[s]  = keys[s,:] . q
//   cos[s]   = dots[s] / (||q|| * ||keys[s,:]||)
//   ctx[h]   = sum_s cos[s] * keys[s,h]
// keys = 32768 x 1024 f32 (128 MiB) -> HBM-bound, single pass over keys.
//
// R2: revert main loop to the R0-proven 1-row prefetch pipeline (R1's
// 2-row/4-chain interleave regressed ~18% on the main kernel: shfl-chain
// latency was already hidden by 8 waves/CU; extra 64 VGPR of row state
// only hurt scheduling). Keep R1's lean epilogue: no out-memset, 16-block
// atomic-free reduce that writes every output element directly.

constexpr int H   = 1024;   // hidden dim (fixed by problem)
constexpr int TPB = 256;    // 4 waves per block
constexpr int WPB = TPB / 64;
constexpr int NBLOCKS = 512;       // 2048 waves = 8 waves/CU (2 blocks/CU)
constexpr int RED_BLOCKS = H / 64; // 16 reduce blocks, 64 cols each

// One row per wave: lane holds columns {j*256 + 4*lane + k}, j=0..3, k=0..3
// (four fully-coalesced float4 loads per row).

template <bool USE_WS>
__global__ __launch_bounds__(TPB, 2)
void cosctx_main(const float* __restrict__ q,
                 const float* __restrict__ keys,
                 int S,
                 float* __restrict__ out,
                 float* __restrict__ ws)
{
    const int lane  = threadIdx.x & 63;
    const int wave  = threadIdx.x >> 6;
    const int gwave = blockIdx.x * WPB + wave;
    const int nwaves = gridDim.x * WPB;

    const float4* q4 = reinterpret_cast<const float4*>(q);
    const float4* k4 = reinterpret_cast<const float4*>(keys);

    // --- query fragment + 1/||q|| (redundant per wave; q is 4 KiB, L2-hot) ---
    float4 qv[4];
#pragma unroll
    for (int j = 0; j < 4; ++j) qv[j] = q4[j * 64 + lane];

    float qsq = 0.f;
#pragma unroll
    for (int j = 0; j < 4; ++j)
        qsq += qv[j].x * qv[j].x + qv[j].y * qv[j].y +
               qv[j].z * qv[j].z + qv[j].w * qv[j].w;
#pragma unroll
    for (int off = 32; off > 0; off >>= 1) qsq += __shfl_down(qsq, off, 64);
    const float inv_qn = rsqrtf(__shfl(qsq, 0, 64));

    float4 acc[4];
#pragma unroll
    for (int j = 0; j < 4; ++j) acc[j] = make_float4(0.f, 0.f, 0.f, 0.f);

    // --- single pass over rows, 1-row prefetch pipeline ---
    int row = gwave;
    float4 kv[4];
    if (row < S) {
        const float4* kr = k4 + (size_t)row * (H / 4);
#pragma unroll
        for (int j = 0; j < 4; ++j) kv[j] = kr[j * 64 + lane];
    }
    while (row < S) {
        const int nrow = row + nwaves;
        float4 kn[4];
        if (nrow < S) {
            const float4* kr = k4 + (size_t)nrow * (H / 4);
#pragma unroll
            for (int j = 0; j < 4; ++j) kn[j] = kr[j * 64 + lane];
        }

        float dot = 0.f, ksq = 0.f;
#pragma unroll
        for (int j = 0; j < 4; ++j) {
            dot += kv[j].x * qv[j].x + kv[j].y * qv[j].y +
                   kv[j].z * qv[j].z + kv[j].w * qv[j].w;
            ksq += kv[j].x * kv[j].x + kv[j].y * kv[j].y +
                   kv[j].z * kv[j].z + kv[j].w * kv[j].w;
        }
        // two interleaved (independent) shuffle-reduce chains, no barriers
#pragma unroll
        for (int off = 32; off > 0; off >>= 1) {
            dot += __shfl_down(dot, off, 64);
            ksq += __shfl_down(ksq, off, 64);
        }
        const float score = __shfl(dot, 0, 64) * inv_qn *
                            rsqrtf(__shfl(ksq, 0, 64));

#pragma unroll
        for (int j = 0; j < 4; ++j) {
            acc[j].x += score * kv[j].x;
            acc[j].y += score * kv[j].y;
            acc[j].z += score * kv[j].z;
            acc[j].w += score * kv[j].w;
        }
#pragma unroll
        for (int j = 0; j < 4; ++j) kv[j] = kn[j];
        row = nrow;
    }

    // --- block reduce: 4 wave-partials -> 1 block-partial [H] ---
    __shared__ float sacc[WPB][H];   // 16 KiB
    float4* sa4 = reinterpret_cast<float4*>(sacc[wave]);
#pragma unroll
    for (int j = 0; j < 4; ++j) sa4[j * 64 + lane] = acc[j];
    __syncthreads();

    float4 v = make_float4(0.f, 0.f, 0.f, 0.f);
#pragma unroll
    for (int w = 0; w < WPB; ++w) {
        float4 u = reinterpret_cast<const float4*>(sacc[w])[threadIdx.x];
        v.x += u.x; v.y += u.y; v.z += u.z; v.w += u.w;
    }

    if (USE_WS) {
        // block-partial to workspace, non-atomic; reduced by second kernel
        reinterpret_cast<float4*>(ws)[(size_t)blockIdx.x * (H / 4) + threadIdx.x] = v;
    } else {
        // fallback: device-scope atomics straight into out (out pre-zeroed)
        const int c = threadIdx.x * 4;
        atomicAdd(out + c + 0, v.x);
        atomicAdd(out + c + 1, v.y);
        atomicAdd(out + c + 2, v.z);
        atomicAdd(out + c + 3, v.w);
    }
}

// Reduce NBLOCKS x H block-partials (2 MiB, L2/L3-hot) into out.
// 16 blocks, one per 64-column slab; no atomics, writes out directly
// (covers all H columns -> no out-memset needed).
__global__ __launch_bounds__(256)
void cosctx_reduce(const float* __restrict__ ws, float* __restrict__ out)
{
    const float4* w4 = reinterpret_cast<const float4*>(ws);
    const int cq = threadIdx.x & 15;          // col-quad within 64-col slab
    const int rg = threadIdx.x >> 4;          // 0..15 row-group
    const int base = blockIdx.x * 16 + cq;    // float4 index within a row

    float4 s = make_float4(0.f, 0.f, 0.f, 0.f);
    for (int b = rg; b < NBLOCKS; b += 16) {
        float4 u = w4[(size_t)b * (H / 4) + base];
        s.x += u.x; s.y += u.y; s.z += u.z; s.w += u.w;
    }

    __shared__ float4 red[16][16];
    red[rg][cq] = s;
    __syncthreads();

    if (threadIdx.x < 16) {
        float4 r = red[0][threadIdx.x];
#pragma unroll
        for (int g = 1; g < 16; ++g) {
            float4 u = red[g][threadIdx.x];
            r.x += u.x; r.y += u.y; r.z += u.z; r.w += u.w;
        }
        reinterpret_cast<float4*>(out)[blockIdx.x * 16 + threadIdx.x] = r;
    }
}

extern "C" void kernel_launch(void* const* d_in, const int* in_sizes, int n_in,
                              void* d_out, int out_size, void* d_ws, size_t ws_size,
                              hipStream_t stream)
{
    const float* q    = (const float*)d_in[0];
    const float* keys = (const float*)d_in[1];
    float* out        = (float*)d_out;
    const int S = in_sizes[1] / H;

    const size_t ws_need = (size_t)NBLOCKS * H * sizeof(float);
    if (ws_size >= ws_need) {
        // no out-memset: cosctx_reduce writes every output element directly
        cosctx_main<true><<<NBLOCKS, TPB, 0, stream>>>(q, keys, S, out, (float*)d_ws);
        cosctx_reduce<<<RED_BLOCKS, 256, 0, stream>>>((const float*)d_ws, out);
    } else {
        // fallback: d_out poisoned 0xAA before every call -> zero it, then atomics
        hipMemsetAsync(out, 0, H * sizeof(float), stream);
        cosctx_main<false><<<NBLOCKS, TPB, 0, stream>>>(q, keys, S, out, nullptr);
    }
}